// Round 2
// baseline (2771.446 us; speedup 1.0000x reference)
//
#include <hip/hip_runtime.h>

#define DIM 768
#define NHEADS 12
#define NTOK 197
#define BATCH 128
#define B_CH 32                     // batch chunk (4 chunks) -> ws ~79 MB
#define NCHUNK (BATCH / B_CH)
#define M_C (B_CH * NTOK)           // 6304 rows per chunk

// ---------------- GEMM: C = A @ W^T + bias ----------------
// A [M,K] row-major, W [Nn,K] row-major. BM=BN=128, BK=16, 256 thr, 8x8/thread.
// M may be non-multiple of BM: loads clamp row, stores guard.
#define BM 128
#define BN 128
#define BK 16

template<int MODE>  // 0: plain C[M,Nn];  1: qkv scatter to chunk-local q/k/v [B_CH,H,N,64] (q pre-scaled)
__global__ __launch_bounds__(256)
void gemm_kernel(const float* __restrict__ A, const float* __restrict__ W,
                 const float* __restrict__ bias, float* __restrict__ C0,
                 float* __restrict__ Cq, float* __restrict__ Ck, float* __restrict__ Cv,
                 int M, int Nn, int K)
{
    __shared__ float As[BK][BM];
    __shared__ float Bs[BK][BN];
    const int tid = threadIdx.x;
    const int tx = tid & 15, ty = tid >> 4;
    const int rowBase = blockIdx.y * BM;
    const int colBase = blockIdx.x * BN;
    float acc[8][8] = {};

    for (int kt = 0; kt < K; kt += BK) {
#pragma unroll
        for (int l = 0; l < 2; ++l) {
            const int li = tid + l * 256;
            const int r  = li >> 2;          // 0..127
            const int c4 = (li & 3) << 2;    // 0,4,8,12
            int grow = rowBase + r;
            if (grow >= M) grow = M - 1;     // clamp (discarded at store)
            float4 av = *reinterpret_cast<const float4*>(&A[(size_t)grow * K + kt + c4]);
            As[c4 + 0][r] = av.x; As[c4 + 1][r] = av.y; As[c4 + 2][r] = av.z; As[c4 + 3][r] = av.w;
            float4 wv = *reinterpret_cast<const float4*>(&W[(size_t)(colBase + r) * K + kt + c4]);
            Bs[c4 + 0][r] = wv.x; Bs[c4 + 1][r] = wv.y; Bs[c4 + 2][r] = wv.z; Bs[c4 + 3][r] = wv.w;
        }
        __syncthreads();
#pragma unroll
        for (int k = 0; k < BK; ++k) {
            float a[8], b[8];
            *(float4*)&a[0] = *(const float4*)&As[k][ty * 8];
            *(float4*)&a[4] = *(const float4*)&As[k][ty * 8 + 4];
            *(float4*)&b[0] = *(const float4*)&Bs[k][tx * 8];
            *(float4*)&b[4] = *(const float4*)&Bs[k][tx * 8 + 4];
#pragma unroll
            for (int i = 0; i < 8; ++i)
#pragma unroll
                for (int j = 0; j < 8; ++j)
                    acc[i][j] += a[i] * b[j];
        }
        __syncthreads();
    }

    const int col0 = colBase + tx * 8;
    if (MODE == 0) {
#pragma unroll
        for (int i = 0; i < 8; ++i) {
            const int r = rowBase + ty * 8 + i;
            if (r < M) {
#pragma unroll
                for (int j = 0; j < 8; j += 4) {
                    float4 o;
                    o.x = acc[i][j + 0] + bias[col0 + j + 0];
                    o.y = acc[i][j + 1] + bias[col0 + j + 1];
                    o.z = acc[i][j + 2] + bias[col0 + j + 2];
                    o.w = acc[i][j + 3] + bias[col0 + j + 3];
                    *(float4*)&C0[(size_t)r * Nn + col0 + j] = o;
                }
            }
        }
    } else {
        // col0 is a multiple of 8; all 8 columns share (s,h). d0 in {0,8,...,56}.
        const int s   = col0 / DIM;
        const int rem = col0 - s * DIM;
        const int h   = rem >> 6;
        const int d0  = rem & 63;
        float* dst = (s == 0) ? Cq : (s == 1) ? Ck : Cv;
        const float mul = (s == 0) ? 0.125f : 1.0f;  // scale = 64^-0.5 baked into q
#pragma unroll
        for (int i = 0; i < 8; ++i) {
            const int r = rowBase + ty * 8 + i;      // chunk-local row
            if (r < M) {
                const int b = r / NTOK;              // chunk-local batch 0..B_CH-1
                const int n = r - b * NTOK;
                float* drow = dst + (((size_t)(b * NHEADS + h) * NTOK + n) << 6) + d0;
#pragma unroll
                for (int j = 0; j < 8; j += 4) {
                    float4 o;
                    o.x = (acc[i][j + 0] + bias[col0 + j + 0]) * mul;
                    o.y = (acc[i][j + 1] + bias[col0 + j + 1]) * mul;
                    o.z = (acc[i][j + 2] + bias[col0 + j + 2]) * mul;
                    o.w = (acc[i][j + 3] + bias[col0 + j + 3]) * mul;
                    *(float4*)&drow[j] = o;
                }
            }
        }
    }
}

// ---------------- bias pre-gather: biasT[h][key][query] ----------------
__global__ void bias_pre(const float* __restrict__ table, const int* __restrict__ ridx,
                         float* __restrict__ biasT)
{
    const int li = blockIdx.x * 256 + threadIdx.x;
    if (li >= NHEADS * NTOK * NTOK) return;
    const int q  = li % NTOK;
    const int t2 = li / NTOK;
    const int j  = t2 % NTOK;   // key
    const int h  = t2 / NTOK;
    biasT[li] = table[ridx[q * NTOK + j] * NHEADS + h];
}

// ---------------- fused attention: one block per chunk-local (b,h) ----------------
// Single-pass softmax (no max subtraction): |q.k*scale + bias| is O(2) here, exp safe;
// result is exactly softmax after the final normalization.
__global__ __launch_bounds__(256)
void attn_kernel(const float* __restrict__ Q, const float* __restrict__ K,
                 const float* __restrict__ V, const float* __restrict__ biasT,
                 float* __restrict__ O)
{
    const int bh = blockIdx.x;          // chunk-local
    const int b  = bh / NHEADS;
    const int h  = bh - b * NHEADS;
    __shared__ float Kt[64][64];
    __shared__ float Vt[64][64];
    const int t = threadIdx.x;
    const bool active = t < NTOK;

    const float* qb = Q + (size_t)bh * NTOK * 64;
    float q[64];
    if (active) {
#pragma unroll
        for (int d = 0; d < 64; d += 4)
            *(float4*)&q[d] = *(const float4*)&qb[t * 64 + d];
    }
    const float* bh_bias = biasT + (size_t)h * NTOK * NTOK;  // [key][query]

    float l_sum = 0.f;
    float o[64] = {};
    for (int kt0 = 0; kt0 < NTOK; kt0 += 64) {
        const int cnt = min(64, NTOK - kt0);
        __syncthreads();
        for (int l = t; l < 64 * 16; l += 256) {
            const int r  = l >> 4;
            const int c4 = (l & 15) << 2;
            if (r < cnt) {
                const size_t src = ((size_t)bh * NTOK + kt0 + r) * 64 + c4;
                *(float4*)&Kt[r][c4] = *(const float4*)&K[src];
                *(float4*)&Vt[r][c4] = *(const float4*)&V[src];
            }
        }
        __syncthreads();
        if (active) {
            for (int j = 0; j < cnt; ++j) {
                float s = bh_bias[(kt0 + j) * NTOK + t];  // lane-coalesced
#pragma unroll
                for (int d = 0; d < 64; d += 4) {
                    float4 kv = *(const float4*)&Kt[j][d];  // broadcast
                    s += q[d + 0] * kv.x + q[d + 1] * kv.y + q[d + 2] * kv.z + q[d + 3] * kv.w;
                }
                const float p = __expf(s);
                l_sum += p;
#pragma unroll
                for (int d = 0; d < 64; d += 4) {
                    float4 vv = *(const float4*)&Vt[j][d];  // broadcast
                    o[d + 0] += p * vv.x; o[d + 1] += p * vv.y;
                    o[d + 2] += p * vv.z; o[d + 3] += p * vv.w;
                }
            }
        }
    }
    if (active) {
        const float inv = 1.f / l_sum;
        float* orow = O + ((size_t)b * NTOK + t) * DIM + h * 64;  // chunk-local ao
#pragma unroll
        for (int d = 0; d < 64; d += 4) {
            float4 ov;
            ov.x = o[d + 0] * inv; ov.y = o[d + 1] * inv;
            ov.z = o[d + 2] * inv; ov.w = o[d + 3] * inv;
            *(float4*)&orow[d] = ov;
        }
    }
}

extern "C" void kernel_launch(void* const* d_in, const int* in_sizes, int n_in,
                              void* d_out, int out_size, void* d_ws, size_t ws_size,
                              hipStream_t stream)
{
    const float* x      = (const float*)d_in[0];
    const float* qkv_w  = (const float*)d_in[1];
    const float* qkv_b  = (const float*)d_in[2];
    const float* proj_w = (const float*)d_in[3];
    const float* proj_b = (const float*)d_in[4];
    const float* table  = (const float*)d_in[5];
    const int*   ridx   = (const int*)d_in[6];
    float* out = (float*)d_out;

    // chunk-local buffers: 4 x 19.37 MB + 1.86 MB bias = ~79.3 MB of d_ws
    const size_t QCH = (size_t)B_CH * NHEADS * NTOK * 64;  // 4,841,472 floats
    float* qd    = (float*)d_ws;
    float* kd    = qd + QCH;
    float* vd    = kd + QCH;
    float* ao    = vd + QCH;
    float* biasT = ao + QCH;

    bias_pre<<<(NHEADS * NTOK * NTOK + 255) / 256, 256, 0, stream>>>(table, ridx, biasT);

    for (int c = 0; c < NCHUNK; ++c) {
        const float* xc   = x   + (size_t)c * M_C * DIM;
        float*       outc = out + (size_t)c * M_C * DIM;

        dim3 g1(3 * DIM / BN, (M_C + BM - 1) / BM);   // 18 x 50
        gemm_kernel<1><<<g1, 256, 0, stream>>>(xc, qkv_w, qkv_b, nullptr, qd, kd, vd,
                                               M_C, 3 * DIM, DIM);

        attn_kernel<<<B_CH * NHEADS, 256, 0, stream>>>(qd, kd, vd, biasT, ao);

        dim3 g2(DIM / BN, (M_C + BM - 1) / BM);       // 6 x 50
        gemm_kernel<0><<<g2, 256, 0, stream>>>(ao, proj_w, proj_b, outc,
                                               nullptr, nullptr, nullptr,
                                               M_C, DIM, DIM);
    }
}

// Round 3
// 2727.758 us; speedup vs baseline: 1.0160x; 1.0160x over previous
//
#include <hip/hip_runtime.h>
#include <stdint.h>

#define DIM 768
#define NHEADS 12
#define NTOK 197
#define BATCH 128
#define B_CH 16
#define NCHUNK (BATCH / B_CH)
#define M_C (B_CH * NTOK)          // 3152 rows per chunk

typedef __attribute__((ext_vector_type(8))) short bf16x8;
typedef __attribute__((ext_vector_type(4))) float f32x4;

__device__ __forceinline__ unsigned short f2bf(float f) {
    unsigned u = __float_as_uint(f);
    return (unsigned short)((u + 0x7FFFu + ((u >> 16) & 1u)) >> 16);  // RNE
}
__device__ __forceinline__ float bf2f(unsigned short h) {
    return __uint_as_float(((unsigned)h) << 16);
}

__device__ __forceinline__ void load_lds16(const void* g, void* l) {
    __builtin_amdgcn_global_load_lds(
        (const __attribute__((address_space(1))) unsigned int*)(uintptr_t)g,
        (__attribute__((address_space(3))) unsigned int*)(uintptr_t)l, 16, 0, 0);
}

// ---------------- split fp32 -> bf16 hi/lo ----------------
__global__ __launch_bounds__(256) void split_bf16(const float* __restrict__ in,
                                                  unsigned short* __restrict__ hi,
                                                  unsigned short* __restrict__ lo, int n4)
{
    const int i = blockIdx.x * 256 + threadIdx.x;
    if (i >= n4) return;
    float4 v = ((const float4*)in)[i];
    ushort4 h, l;
    h.x = f2bf(v.x); l.x = f2bf(v.x - bf2f(h.x));
    h.y = f2bf(v.y); l.y = f2bf(v.y - bf2f(h.y));
    h.z = f2bf(v.z); l.z = f2bf(v.z - bf2f(h.z));
    h.w = f2bf(v.w); l.w = f2bf(v.w - bf2f(h.w));
    ((ushort4*)hi)[i] = h;
    ((ushort4*)lo)[i] = l;
}

// ---------------- bf16x3 MFMA GEMM: C = (Ah+Al) @ (Bh+Bl)^T + bias ----------------
// A [M,K] bf16 hi/lo row-major, W [Nn,K] bf16 hi/lo row-major.
// 128x128 tile, BK=32, 256 thr = 4 waves (2x2 of 64x64), mfma_f32_16x16x32_bf16.
// LDS 32 KB, fragment-ordered: tile(4: Ah,Al,Bh,Bl) x [blk16(8)][kc(4)][r(16)] x 16B.
template<int MODE>  // 0: C0[M,Nn]; 1: qkv scatter to q/k/v [B_CH,H,N,64], q pre-scaled
__global__ __launch_bounds__(256)
void gemm_bf16x3(const unsigned short* __restrict__ Ah, const unsigned short* __restrict__ Al,
                 const unsigned short* __restrict__ Bh, const unsigned short* __restrict__ Bl,
                 const float* __restrict__ bias,
                 float* __restrict__ C0, float* __restrict__ Cq,
                 float* __restrict__ Ck, float* __restrict__ Cv,
                 int M, int Nn, int K)
{
    __shared__ bf16x8 lds[2048];   // 32 KB
    const int tid = threadIdx.x;
    const int rowBase = blockIdx.y * 128;
    const int colBase = blockIdx.x * 128;

    // per-thread staging sources: 8 slots of 16B, LDS slot s = tid + t*256 (lane-linear)
    const unsigned short* srcs[8];
#pragma unroll
    for (int t = 0; t < 8; ++t) {
        const int s = tid + t * 256;
        const int tile = s >> 9;          // 0:Ah 1:Al 2:Bh 3:Bl
        const int w = s & 511;
        const int rl = ((w >> 6) << 4) | (w & 15);   // row within tile 0..127
        const int kc = (w >> 4) & 3;                 // k-chunk (8 bf16)
        if (tile < 2) {
            int grow = rowBase + rl; if (grow >= M) grow = M - 1;   // clamp
            srcs[t] = (tile == 0 ? Ah : Al) + (size_t)grow * K + kc * 8;
        } else {
            const int gcol = colBase + rl;
            srcs[t] = (tile == 2 ? Bh : Bl) + (size_t)gcol * K + kc * 8;
        }
    }

    const int lane = tid & 63, wid = tid >> 6;
    const int wr = wid >> 1, wc = wid & 1;
    const int lr = lane & 15, lk = lane >> 4;

    f32x4 acc[4][4];
#pragma unroll
    for (int i = 0; i < 4; ++i)
#pragma unroll
        for (int j = 0; j < 4; ++j) acc[i][j] = (f32x4){0.f, 0.f, 0.f, 0.f};

    for (int kt = 0; kt < K; kt += 32) {
        __syncthreads();
#pragma unroll
        for (int t = 0; t < 8; ++t) {
            const int s = tid + t * 256;
            load_lds16(srcs[t] + kt, &lds[s]);
        }
        asm volatile("s_waitcnt vmcnt(0)" ::: "memory");
        __syncthreads();

        bf16x8 ah[4], al[4], bh[4], bl[4];
#pragma unroll
        for (int i = 0; i < 4; ++i) {
            const int am = ((wr * 4 + i) * 4 + lk) * 16 + lr;
            ah[i] = lds[0 * 512 + am];
            al[i] = lds[1 * 512 + am];
            const int bn = ((wc * 4 + i) * 4 + lk) * 16 + lr;
            bh[i] = lds[2 * 512 + bn];
            bl[i] = lds[3 * 512 + bn];
        }
#pragma unroll
        for (int mi = 0; mi < 4; ++mi)
#pragma unroll
            for (int ni = 0; ni < 4; ++ni) {
                acc[mi][ni] = __builtin_amdgcn_mfma_f32_16x16x32_bf16(ah[mi], bh[ni], acc[mi][ni], 0, 0, 0);
                acc[mi][ni] = __builtin_amdgcn_mfma_f32_16x16x32_bf16(ah[mi], bl[ni], acc[mi][ni], 0, 0, 0);
                acc[mi][ni] = __builtin_amdgcn_mfma_f32_16x16x32_bf16(al[mi], bh[ni], acc[mi][ni], 0, 0, 0);
            }
    }

    // C/D layout: col = lane&15, row = (lane>>4)*4 + i   [m89 verified]
    const int rbase = rowBase + wr * 64 + lk * 4;
    if (MODE == 0) {
#pragma unroll
        for (int mi = 0; mi < 4; ++mi)
#pragma unroll
            for (int ni = 0; ni < 4; ++ni) {
                const int c = colBase + wc * 64 + ni * 16 + lr;
                const float bv = bias[c];
#pragma unroll
                for (int i = 0; i < 4; ++i) {
                    const int r = rbase + mi * 16 + i;
                    if (r < M) C0[(size_t)r * Nn + c] = acc[mi][ni][i] + bv;
                }
            }
    } else {
#pragma unroll
        for (int ni = 0; ni < 4; ++ni) {
            const int c0 = colBase + wc * 64 + ni * 16;        // fragment col base (mult of 16)
            const int s = c0 / DIM;
            const int rem = c0 - s * DIM;
            const int h = rem >> 6;
            const int d = (rem & 63) + lr;
            float* dst = (s == 0) ? Cq : (s == 1) ? Ck : Cv;
            const float mul = (s == 0) ? 0.125f : 1.0f;        // q pre-scaled by 64^-0.5
            const float bv = bias[c0 + lr];
#pragma unroll
            for (int mi = 0; mi < 4; ++mi)
#pragma unroll
                for (int i = 0; i < 4; ++i) {
                    const int r = rbase + mi * 16 + i;
                    if (r < M) {
                        const int b = r / NTOK;
                        const int n = r - b * NTOK;
                        dst[(((size_t)(b * NHEADS + h) * NTOK + n) << 6) + d] =
                            (acc[mi][ni][i] + bv) * mul;
                    }
                }
        }
    }
}

// ---------------- bias pre-gather: biasT[h][key][query] ----------------
__global__ void bias_pre(const float* __restrict__ table, const int* __restrict__ ridx,
                         float* __restrict__ biasT)
{
    const int li = blockIdx.x * 256 + threadIdx.x;
    if (li >= NHEADS * NTOK * NTOK) return;
    const int q  = li % NTOK;
    const int t2 = li / NTOK;
    const int j  = t2 % NTOK;
    const int h  = t2 / NTOK;
    biasT[li] = table[ridx[q * NTOK + j] * NHEADS + h];
}

// ---------------- fused attention, writes bf16 hi/lo output ----------------
__global__ __launch_bounds__(256)
void attn_kernel(const float* __restrict__ Q, const float* __restrict__ K,
                 const float* __restrict__ V, const float* __restrict__ biasT,
                 unsigned short* __restrict__ Oh, unsigned short* __restrict__ Ol)
{
    const int bh = blockIdx.x;
    const int b  = bh / NHEADS;
    const int h  = bh - b * NHEADS;
    __shared__ float Kt[64][64];
    __shared__ float Vt[64][64];
    const int t = threadIdx.x;
    const bool active = t < NTOK;

    const float* qb = Q + (size_t)bh * NTOK * 64;
    float q[64];
    if (active) {
#pragma unroll
        for (int d = 0; d < 64; d += 4)
            *(float4*)&q[d] = *(const float4*)&qb[t * 64 + d];
    }
    const float* bh_bias = biasT + (size_t)h * NTOK * NTOK;

    float l_sum = 0.f;
    float o[64] = {};
    for (int kt0 = 0; kt0 < NTOK; kt0 += 64) {
        const int cnt = min(64, NTOK - kt0);
        __syncthreads();
        for (int l = t; l < 64 * 16; l += 256) {
            const int r  = l >> 4;
            const int c4 = (l & 15) << 2;
            if (r < cnt) {
                const size_t src = ((size_t)bh * NTOK + kt0 + r) * 64 + c4;
                *(float4*)&Kt[r][c4] = *(const float4*)&K[src];
                *(float4*)&Vt[r][c4] = *(const float4*)&V[src];
            }
        }
        __syncthreads();
        if (active) {
            for (int j = 0; j < cnt; ++j) {
                float s = bh_bias[(kt0 + j) * NTOK + t];
#pragma unroll
                for (int d = 0; d < 64; d += 4) {
                    float4 kv = *(const float4*)&Kt[j][d];
                    s += q[d + 0] * kv.x + q[d + 1] * kv.y + q[d + 2] * kv.z + q[d + 3] * kv.w;
                }
                const float p = __expf(s);
                l_sum += p;
#pragma unroll
                for (int d = 0; d < 64; d += 4) {
                    float4 vv = *(const float4*)&Vt[j][d];
                    o[d + 0] += p * vv.x; o[d + 1] += p * vv.y;
                    o[d + 2] += p * vv.z; o[d + 3] += p * vv.w;
                }
            }
        }
    }
    if (active) {
        const float inv = 1.f / l_sum;
        const size_t ob = ((size_t)(b * NTOK + t)) * DIM + h * 64;
#pragma unroll
        for (int d = 0; d < 64; d += 4) {
            ushort4 hv, lv;
            float v0 = o[d + 0] * inv, v1 = o[d + 1] * inv, v2 = o[d + 2] * inv, v3 = o[d + 3] * inv;
            hv.x = f2bf(v0); lv.x = f2bf(v0 - bf2f(hv.x));
            hv.y = f2bf(v1); lv.y = f2bf(v1 - bf2f(hv.y));
            hv.z = f2bf(v2); lv.z = f2bf(v2 - bf2f(hv.z));
            hv.w = f2bf(v3); lv.w = f2bf(v3 - bf2f(hv.w));
            *(ushort4*)&Oh[ob + d] = hv;
            *(ushort4*)&Ol[ob + d] = lv;
        }
    }
}

extern "C" void kernel_launch(void* const* d_in, const int* in_sizes, int n_in,
                              void* d_out, int out_size, void* d_ws, size_t ws_size,
                              hipStream_t stream)
{
    const float* x      = (const float*)d_in[0];
    const float* qkv_w  = (const float*)d_in[1];
    const float* qkv_b  = (const float*)d_in[2];
    const float* proj_w = (const float*)d_in[3];
    const float* proj_b = (const float*)d_in[4];
    const float* table  = (const float*)d_in[5];
    const int*   ridx   = (const int*)d_in[6];
    float* out = (float*)d_out;

    // workspace layout (~50 MB total)
    char* p = (char*)d_ws;
    auto alloc = [&](size_t bytes) { char* r = p; p += (bytes + 255) & ~(size_t)255; return r; };
    unsigned short* wqh = (unsigned short*)alloc((size_t)3 * DIM * DIM * 2);
    unsigned short* wql = (unsigned short*)alloc((size_t)3 * DIM * DIM * 2);
    unsigned short* wph = (unsigned short*)alloc((size_t)DIM * DIM * 2);
    unsigned short* wpl = (unsigned short*)alloc((size_t)DIM * DIM * 2);
    float* biasT        = (float*)alloc((size_t)NHEADS * NTOK * NTOK * 4);
    unsigned short* xh  = (unsigned short*)alloc((size_t)M_C * DIM * 2);   // reused as ao_hi
    unsigned short* xl  = (unsigned short*)alloc((size_t)M_C * DIM * 2);   // reused as ao_lo
    float* qd           = (float*)alloc((size_t)B_CH * NHEADS * NTOK * 64 * 4);
    float* kd           = (float*)alloc((size_t)B_CH * NHEADS * NTOK * 64 * 4);
    float* vd           = (float*)alloc((size_t)B_CH * NHEADS * NTOK * 64 * 4);

    split_bf16<<<(3 * DIM * DIM / 4 + 255) / 256, 256, 0, stream>>>(qkv_w, wqh, wql, 3 * DIM * DIM / 4);
    split_bf16<<<(DIM * DIM / 4 + 255) / 256, 256, 0, stream>>>(proj_w, wph, wpl, DIM * DIM / 4);
    bias_pre<<<(NHEADS * NTOK * NTOK + 255) / 256, 256, 0, stream>>>(table, ridx, biasT);

    const int mtiles = (M_C + 127) / 128;   // 25
    for (int c = 0; c < NCHUNK; ++c) {
        const float* xc   = x   + (size_t)c * M_C * DIM;
        float*       outc = out + (size_t)c * M_C * DIM;

        split_bf16<<<(M_C * DIM / 4 + 255) / 256, 256, 0, stream>>>(xc, xh, xl, M_C * DIM / 4);

        gemm_bf16x3<1><<<dim3(3 * DIM / 128, mtiles), 256, 0, stream>>>(
            xh, xl, wqh, wql, qkv_b, nullptr, qd, kd, vd, M_C, 3 * DIM, DIM);

        attn_kernel<<<B_CH * NHEADS, 256, 0, stream>>>(qd, kd, vd, biasT, xh, xl);

        gemm_bf16x3<0><<<dim3(DIM / 128, mtiles), 256, 0, stream>>>(
            xh, xl, wph, wpl, proj_b, outc, nullptr, nullptr, nullptr, M_C, DIM, DIM);
    }
}

// Round 5
// 1007.204 us; speedup vs baseline: 2.7516x; 2.7082x over previous
//
#include <hip/hip_runtime.h>
#include <stdint.h>

#define DIM 768
#define NHEADS 12
#define NTOK 197
#define BATCH 128
#define B_Q 32                      // quarter-batch
#define NQUARTER (BATCH / B_Q)
#define M_C (B_Q * NTOK)            // 6304 rows per quarter

typedef __attribute__((ext_vector_type(8))) short bf16x8;
typedef __attribute__((ext_vector_type(4))) float f32x4;

__device__ __forceinline__ unsigned short f2bf(float f) {
    unsigned u = __float_as_uint(f);
    return (unsigned short)((u + 0x7FFFu + ((u >> 16) & 1u)) >> 16);  // RNE
}
__device__ __forceinline__ float bf2f(unsigned short h) {
    return __uint_as_float(((unsigned)h) << 16);
}

__device__ __forceinline__ void load_lds16(const void* g, void* l) {
    __builtin_amdgcn_global_load_lds(
        (const __attribute__((address_space(1))) unsigned int*)(uintptr_t)g,
        (__attribute__((address_space(3))) unsigned int*)(uintptr_t)l, 16, 0, 0);
}

// ---------------- split fp32 -> bf16 hi/lo ----------------
__global__ __launch_bounds__(256) void split_bf16(const float* __restrict__ in,
                                                  unsigned short* __restrict__ hi,
                                                  unsigned short* __restrict__ lo, int n4)
{
    const int i = blockIdx.x * 256 + threadIdx.x;
    if (i >= n4) return;
    float4 v = ((const float4*)in)[i];
    ushort4 h, l;
    h.x = f2bf(v.x); l.x = f2bf(v.x - bf2f(h.x));
    h.y = f2bf(v.y); l.y = f2bf(v.y - bf2f(h.y));
    h.z = f2bf(v.z); l.z = f2bf(v.z - bf2f(h.z));
    h.w = f2bf(v.w); l.w = f2bf(v.w - bf2f(h.w));
    ((ushort4*)hi)[i] = h;
    ((ushort4*)lo)[i] = l;
}

// ---------------- bf16x3 MFMA GEMM: C = (Ah+Al) @ (Bh+Bl)^T + bias ----------------
// MODE 0: fp32 C0[M,Nn].  MODE 1: qkv scatter to bf16 q/k/v [B_Q,H,N,64], q pre-scaled.
template<int MODE>
__global__ __launch_bounds__(256)
void gemm_bf16x3(const unsigned short* __restrict__ Ah, const unsigned short* __restrict__ Al,
                 const unsigned short* __restrict__ Bh, const unsigned short* __restrict__ Bl,
                 const float* __restrict__ bias,
                 float* __restrict__ C0, unsigned short* __restrict__ Cq,
                 unsigned short* __restrict__ Ck, unsigned short* __restrict__ Cv,
                 int M, int Nn, int K)
{
    __shared__ bf16x8 lds[2048];   // 32 KB
    const int tid = threadIdx.x;
    const int rowBase = blockIdx.y * 128;
    const int colBase = blockIdx.x * 128;

    const unsigned short* srcs[8];
#pragma unroll
    for (int t = 0; t < 8; ++t) {
        const int s = tid + t * 256;
        const int tile = s >> 9;          // 0:Ah 1:Al 2:Bh 3:Bl
        const int w = s & 511;
        const int rl = ((w >> 6) << 4) | (w & 15);
        const int kc = (w >> 4) & 3;
        if (tile < 2) {
            int grow = rowBase + rl; if (grow >= M) grow = M - 1;
            srcs[t] = (tile == 0 ? Ah : Al) + (size_t)grow * K + kc * 8;
        } else {
            const int gcol = colBase + rl;
            srcs[t] = (tile == 2 ? Bh : Bl) + (size_t)gcol * K + kc * 8;
        }
    }

    const int lane = tid & 63, wid = tid >> 6;
    const int wr = wid >> 1, wc = wid & 1;
    const int lr = lane & 15, lk = lane >> 4;

    f32x4 acc[4][4];
#pragma unroll
    for (int i = 0; i < 4; ++i)
#pragma unroll
        for (int j = 0; j < 4; ++j) acc[i][j] = (f32x4){0.f, 0.f, 0.f, 0.f};

    for (int kt = 0; kt < K; kt += 32) {
        __syncthreads();
#pragma unroll
        for (int t = 0; t < 8; ++t) {
            const int s = tid + t * 256;
            load_lds16(srcs[t] + kt, &lds[s]);
        }
        asm volatile("s_waitcnt vmcnt(0)" ::: "memory");
        __syncthreads();

        bf16x8 ah[4], al[4], bh[4], bl[4];
#pragma unroll
        for (int i = 0; i < 4; ++i) {
            const int am = ((wr * 4 + i) * 4 + lk) * 16 + lr;
            ah[i] = lds[0 * 512 + am];
            al[i] = lds[1 * 512 + am];
            const int bn = ((wc * 4 + i) * 4 + lk) * 16 + lr;
            bh[i] = lds[2 * 512 + bn];
            bl[i] = lds[3 * 512 + bn];
        }
#pragma unroll
        for (int mi = 0; mi < 4; ++mi)
#pragma unroll
            for (int ni = 0; ni < 4; ++ni) {
                acc[mi][ni] = __builtin_amdgcn_mfma_f32_16x16x32_bf16(ah[mi], bh[ni], acc[mi][ni], 0, 0, 0);
                acc[mi][ni] = __builtin_amdgcn_mfma_f32_16x16x32_bf16(ah[mi], bl[ni], acc[mi][ni], 0, 0, 0);
                acc[mi][ni] = __builtin_amdgcn_mfma_f32_16x16x32_bf16(al[mi], bh[ni], acc[mi][ni], 0, 0, 0);
            }
    }

    // C/D: col = lane&15, row = (lane>>4)*4 + i
    const int rbase = rowBase + wr * 64 + lk * 4;
    if (MODE == 0) {
#pragma unroll
        for (int mi = 0; mi < 4; ++mi)
#pragma unroll
            for (int ni = 0; ni < 4; ++ni) {
                const int c = colBase + wc * 64 + ni * 16 + lr;
                const float bv = bias[c];
#pragma unroll
                for (int i = 0; i < 4; ++i) {
                    const int r = rbase + mi * 16 + i;
                    if (r < M) C0[(size_t)r * Nn + c] = acc[mi][ni][i] + bv;
                }
            }
    } else {
#pragma unroll
        for (int ni = 0; ni < 4; ++ni) {
            const int c0 = colBase + wc * 64 + ni * 16;
            const int s = c0 / DIM;
            const int rem = c0 - s * DIM;
            const int hh = rem >> 6;
            const int d = (rem & 63) + lr;
            unsigned short* dst = (s == 0) ? Cq : (s == 1) ? Ck : Cv;
            const float mul = (s == 0) ? 0.125f : 1.0f;   // q pre-scaled by 64^-0.5
            const float bv = bias[c0 + lr];
#pragma unroll
            for (int mi = 0; mi < 4; ++mi)
#pragma unroll
                for (int i = 0; i < 4; ++i) {
                    const int r = rbase + mi * 16 + i;
                    if (r < M) {
                        const int bb = r / NTOK;
                        const int nn = r - bb * NTOK;
                        dst[(((size_t)(bb * NHEADS + hh) * NTOK + nn) << 6) + d] =
                            f2bf((acc[mi][ni][i] + bv) * mul);
                    }
                }
        }
    }
}

// ---------------- bias pre-gather in MFMA fragment order ----------------
// biasF[h][kt(7)][qt(13)][kn(2)][lane(64)][i(4)] bf16; -60 for OOB keys (kills pad via exp)
#define BIASF_U4 (NHEADS * 7 * 13 * 2 * 64)   // 139776 ushort4's
__global__ __launch_bounds__(256)
void biasF_pre(const float* __restrict__ table, const int* __restrict__ ridx,
               ushort4* __restrict__ biasF)
{
    const int idx = blockIdx.x * 256 + threadIdx.x;
    if (idx >= BIASF_U4) return;
    const int l  = idx & 63;
    int t1 = idx >> 6;
    const int kn = t1 & 1;  t1 >>= 1;
    const int qt = t1 % 13; t1 /= 13;
    const int kt = t1 % 7;
    const int h  = t1 / 7;
    const int k = kt * 32 + kn * 16 + (l & 15);
    ushort4 o;
    unsigned short* op = (unsigned short*)&o;
#pragma unroll
    for (int i = 0; i < 4; ++i) {
        const int q = qt * 16 + (l >> 4) * 4 + i;
        float v = -60.0f;
        if (q < NTOK && k < NTOK) v = table[ridx[q * NTOK + k] * NHEADS + h];
        op[i] = f2bf(v);
    }
    biasF[idx] = o;
}

// ---------------- MFMA flash attention: block = (b,h), 4 waves x 64 queries ----------------
// K tile 32 keys staged via global_load_lds (XOR-swizzled source); V^T in padded LDS;
// P through per-wave padded LDS. Single-pass softmax (scores bounded), pad keys killed by bias=-60.
__global__ __launch_bounds__(256, 2)
void attn_mfma(const unsigned short* __restrict__ Q, const unsigned short* __restrict__ K,
               const unsigned short* __restrict__ V, const unsigned short* __restrict__ biasF,
               unsigned short* __restrict__ Oh, unsigned short* __restrict__ Ol)
{
    __shared__ unsigned short Kb[32 * 64];        // 4 KB, xor-swizzled columns
    __shared__ unsigned short Vt[64 * 40];        // 5 KB, padded V^T
    __shared__ unsigned short Pb[4][64 * 40];     // 20.5 KB, per-wave P

    const int bh = blockIdx.x;
    const int b = bh / NHEADS, h = bh - b * NHEADS;
    const int tid = threadIdx.x;
    const int w = tid >> 6, l = tid & 63;
    const int g = l >> 4, r = l & 15;
    const int nmt = (w < 3) ? 4 : 1;              // wave 3: only m-tile 12 (rows 192-196)

    const unsigned short* qb    = Q + (size_t)bh * NTOK * 64;
    const unsigned short* kbase = K + (size_t)bh * NTOK * 64;
    const unsigned short* vbase = V + (size_t)bh * NTOK * 64;

    // Q fragments: row = lane&15, k(d) = (lane>>4)*8+j
    bf16x8 qa[4][2];
#pragma unroll
    for (int mt = 0; mt < 4; ++mt) {
        if (mt >= nmt) break;
        int qrow = 64 * w + 16 * mt + r; if (qrow > 196) qrow = 196;
#pragma unroll
        for (int kd = 0; kd < 2; ++kd)
            qa[mt][kd] = *(const bf16x8*)&qb[qrow * 64 + kd * 32 + g * 8];
    }

    f32x4 o[4][4];
#pragma unroll
    for (int mt = 0; mt < 4; ++mt)
#pragma unroll
        for (int dt = 0; dt < 4; ++dt) o[mt][dt] = (f32x4){0.f, 0.f, 0.f, 0.f};
    float lsum[4][4] = {};

    // staging geometry
    const int krow = tid >> 3;                    // 0..31
    const int kcl  = (tid & 7) * 8;               // physical col (ushorts)
    const int kcg  = kcl ^ ((krow & 7) << 3);     // logical col at this slot
    const int vdd  = tid >> 2;                    // 0..63
    const int vkg  = tid & 3;

    const ushort4* bF4 = (const ushort4*)biasF;

    for (int kt = 0; kt < 7; ++kt) {
        __syncthreads();
        // K stage: LDS linear, source pre-swizzled
        int key = kt * 32 + krow; if (key > 196) key = 196;
        load_lds16(kbase + (size_t)key * 64 + kcg, &Kb[tid * 8]);
        // V^T stage: gather 8 keys for one d
        bf16x8 vv;
        unsigned short* vp = (unsigned short*)&vv;
#pragma unroll
        for (int j = 0; j < 8; ++j) {
            int kj = kt * 32 + vkg * 8 + j; if (kj > 196) kj = 196;
            vp[j] = vbase[(size_t)kj * 64 + vdd];
        }
        *(bf16x8*)&Vt[vdd * 40 + vkg * 8] = vv;
        asm volatile("s_waitcnt vmcnt(0)" ::: "memory");
        __syncthreads();

        // K b-frags (shared across m-tiles)
        bf16x8 kb[2][2];
#pragma unroll
        for (int kn = 0; kn < 2; ++kn)
#pragma unroll
            for (int kd = 0; kd < 2; ++kd)
                kb[kn][kd] = *(bf16x8*)&Kb[(kn * 16 + r) * 64 + ((kd * 32 + g * 8) ^ ((r & 7) << 3))];

        // scores + softmax numerator + P to LDS
#pragma unroll
        for (int mt = 0; mt < 4; ++mt) {
            if (mt >= nmt) break;
            const int qt = w * 4 + mt;
#pragma unroll
            for (int kn = 0; kn < 2; ++kn) {
                f32x4 s = (f32x4){0.f, 0.f, 0.f, 0.f};
                s = __builtin_amdgcn_mfma_f32_16x16x32_bf16(qa[mt][0], kb[kn][0], s, 0, 0, 0);
                s = __builtin_amdgcn_mfma_f32_16x16x32_bf16(qa[mt][1], kb[kn][1], s, 0, 0, 0);
                const ushort4 bb = bF4[(((h * 7 + kt) * 13 + qt) * 2 + kn) * 64 + l];
                const unsigned short* bp = (const unsigned short*)&bb;
#pragma unroll
                for (int i = 0; i < 4; ++i) {
                    const float p = __expf(s[i] + bf2f(bp[i]));
                    lsum[mt][i] += p;
                    Pb[w][(mt * 16 + 4 * g + i) * 40 + kn * 16 + r] = f2bf(p);
                }
            }
        }

        // PV: o += P @ V  (K-dim = 32 keys in one mfma)
        bf16x8 vb[4];
#pragma unroll
        for (int dt = 0; dt < 4; ++dt)
            vb[dt] = *(bf16x8*)&Vt[(dt * 16 + r) * 40 + g * 8];
#pragma unroll
        for (int mt = 0; mt < 4; ++mt) {
            if (mt >= nmt) break;
            bf16x8 pa = *(bf16x8*)&Pb[w][(mt * 16 + r) * 40 + g * 8];
#pragma unroll
            for (int dt = 0; dt < 4; ++dt)
                o[mt][dt] = __builtin_amdgcn_mfma_f32_16x16x32_bf16(pa, vb[dt], o[mt][dt], 0, 0, 0);
        }
    }

    // reduce denominators across the 16 key-lanes
    float inv[4][4];
#pragma unroll
    for (int mt = 0; mt < 4; ++mt) {
        if (mt >= nmt) break;
#pragma unroll
        for (int i = 0; i < 4; ++i) {
            float t = lsum[mt][i];
            t += __shfl_xor(t, 1); t += __shfl_xor(t, 2);
            t += __shfl_xor(t, 4); t += __shfl_xor(t, 8);
            inv[mt][i] = 1.f / t;
        }
    }

    // write ao hi/lo bf16
#pragma unroll
    for (int mt = 0; mt < 4; ++mt) {
        if (mt >= nmt) break;
#pragma unroll
        for (int i = 0; i < 4; ++i) {
            const int q = 64 * w + mt * 16 + 4 * g + i;
            if (q > 196) continue;
            const size_t base = ((size_t)b * NTOK + q) * DIM + h * 64 + r;
#pragma unroll
            for (int dt = 0; dt < 4; ++dt) {
                const float val = o[mt][dt][i] * inv[mt][i];
                const unsigned short hb = f2bf(val);
                Oh[base + dt * 16] = hb;
                Ol[base + dt * 16] = f2bf(val - bf2f(hb));
            }
        }
    }
}

extern "C" void kernel_launch(void* const* d_in, const int* in_sizes, int n_in,
                              void* d_out, int out_size, void* d_ws, size_t ws_size,
                              hipStream_t stream)
{
    const float* x      = (const float*)d_in[0];
    const float* qkv_w  = (const float*)d_in[1];
    const float* qkv_b  = (const float*)d_in[2];
    const float* proj_w = (const float*)d_in[3];
    const float* proj_b = (const float*)d_in[4];
    const float* table  = (const float*)d_in[5];
    const int*   ridx   = (const int*)d_in[6];
    float* out = (float*)d_out;

    // workspace (~59 MB)
    char* p = (char*)d_ws;
    auto alloc = [&](size_t bytes) { char* r = p; p += (bytes + 255) & ~(size_t)255; return r; };
    unsigned short* wqh = (unsigned short*)alloc((size_t)3 * DIM * DIM * 2);
    unsigned short* wql = (unsigned short*)alloc((size_t)3 * DIM * DIM * 2);
    unsigned short* wph = (unsigned short*)alloc((size_t)DIM * DIM * 2);
    unsigned short* wpl = (unsigned short*)alloc((size_t)DIM * DIM * 2);
    ushort4*        bF  = (ushort4*)alloc((size_t)BIASF_U4 * 8);
    unsigned short* xh  = (unsigned short*)alloc((size_t)M_C * DIM * 2);   // reused as ao_hi
    unsigned short* xl  = (unsigned short*)alloc((size_t)M_C * DIM * 2);   // reused as ao_lo
    unsigned short* qd  = (unsigned short*)alloc((size_t)B_Q * NHEADS * NTOK * 64 * 2);
    unsigned short* kd  = (unsigned short*)alloc((size_t)B_Q * NHEADS * NTOK * 64 * 2);
    unsigned short* vd  = (unsigned short*)alloc((size_t)B_Q * NHEADS * NTOK * 64 * 2);

    split_bf16<<<(3 * DIM * DIM / 4 + 255) / 256, 256, 0, stream>>>(qkv_w, wqh, wql, 3 * DIM * DIM / 4);
    split_bf16<<<(DIM * DIM / 4 + 255) / 256, 256, 0, stream>>>(proj_w, wph, wpl, DIM * DIM / 4);
    biasF_pre<<<(BIASF_U4 + 255) / 256, 256, 0, stream>>>(table, ridx, bF);

    const int mtiles = (M_C + 127) / 128;   // 50
    for (int c = 0; c < NQUARTER; ++c) {
        const float* xc   = x   + (size_t)c * M_C * DIM;
        float*       outc = out + (size_t)c * M_C * DIM;

        split_bf16<<<(M_C * DIM / 4 + 255) / 256, 256, 0, stream>>>(xc, xh, xl, M_C * DIM / 4);

        gemm_bf16x3<1><<<dim3(3 * DIM / 128, mtiles), 256, 0, stream>>>(
            xh, xl, wqh, wql, qkv_b, nullptr, qd, kd, vd, M_C, 3 * DIM, DIM);

        attn_mfma<<<B_Q * NHEADS, 256, 0, stream>>>(qd, kd, vd,
                                                    (const unsigned short*)bF, xh, xl);

        gemm_bf16x3<0><<<dim3(DIM / 128, mtiles), 256, 0, stream>>>(
            xh, xl, wph, wpl, proj_b, outc, nullptr, nullptr, nullptr, M_C, DIM, DIM);
    }
}

// Round 6
// 949.773 us; speedup vs baseline: 2.9180x; 1.0605x over previous
//
#include <hip/hip_runtime.h>
#include <stdint.h>

#define DIM 768
#define NHEADS 12
#define NTOK 197
#define BATCH 128
#define B_Q 32                      // quarter-batch
#define NQUARTER (BATCH / B_Q)
#define M_C (B_Q * NTOK)            // 6304 rows per quarter

typedef __attribute__((ext_vector_type(8))) short bf16x8;
typedef __attribute__((ext_vector_type(4))) float f32x4;

__device__ __forceinline__ unsigned short f2bf(float f) {
    unsigned u = __float_as_uint(f);
    return (unsigned short)((u + 0x7FFFu + ((u >> 16) & 1u)) >> 16);  // RNE
}
__device__ __forceinline__ float bf2f(unsigned short h) {
    return __uint_as_float(((unsigned)h) << 16);
}

__device__ __forceinline__ void load_lds16(const void* g, void* l) {
    __builtin_amdgcn_global_load_lds(
        (const __attribute__((address_space(1))) unsigned int*)(uintptr_t)g,
        (__attribute__((address_space(3))) unsigned int*)(uintptr_t)l, 16, 0, 0);
}

// ---------------- split fp32 -> bf16 hi/lo ----------------
__global__ __launch_bounds__(256) void split_bf16(const float* __restrict__ in,
                                                  unsigned short* __restrict__ hi,
                                                  unsigned short* __restrict__ lo, int n4)
{
    const int i = blockIdx.x * 256 + threadIdx.x;
    if (i >= n4) return;
    float4 v = ((const float4*)in)[i];
    ushort4 h, l;
    h.x = f2bf(v.x); l.x = f2bf(v.x - bf2f(h.x));
    h.y = f2bf(v.y); l.y = f2bf(v.y - bf2f(h.y));
    h.z = f2bf(v.z); l.z = f2bf(v.z - bf2f(h.z));
    h.w = f2bf(v.w); l.w = f2bf(v.w - bf2f(h.w));
    ((ushort4*)hi)[i] = h;
    ((ushort4*)lo)[i] = l;
}

// ---------------- bf16x3 MFMA GEMM: C = (Ah+Al) @ (Bh+Bl)^T + bias ----------------
// 2-phase double-buffered pipeline (T3 minimum) + bijective XCD swizzle (T1/m204).
// MODE 0: fp32 C0[M,Nn].  MODE 1: qkv scatter to bf16 q/k/v [B_Q,H,N,64], q pre-scaled.
template<int MODE>
__global__ __launch_bounds__(256)
void gemm_bf16x3(const unsigned short* __restrict__ Ah, const unsigned short* __restrict__ Al,
                 const unsigned short* __restrict__ Bh, const unsigned short* __restrict__ Bl,
                 const float* __restrict__ bias,
                 float* __restrict__ C0, unsigned short* __restrict__ Cq,
                 unsigned short* __restrict__ Ck, unsigned short* __restrict__ Cv,
                 int M, int Nn, int K)
{
    __shared__ bf16x8 lds[2][2048];   // 64 KB double-buffered
    const int tid = threadIdx.x;

    // bijective XCD swizzle: contiguous wg-chunk per XCD -> A-panel L2 locality
    const int gx = gridDim.x;
    const int nwg = gx * gridDim.y;
    const int orig = blockIdx.y * gx + blockIdx.x;
    const int q8 = nwg >> 3, r8 = nwg & 7;
    const int xcd = orig & 7, pos = orig >> 3;
    const int wg = (xcd < r8 ? xcd * (q8 + 1) : r8 * (q8 + 1) + (xcd - r8) * q8) + pos;
    const int rowBase = (wg / gx) * 128;
    const int colBase = (wg % gx) * 128;

    const unsigned short* srcs[8];
#pragma unroll
    for (int t = 0; t < 8; ++t) {
        const int s = tid + t * 256;
        const int tile = s >> 9;          // 0:Ah 1:Al 2:Bh 3:Bl
        const int w = s & 511;
        const int rl = ((w >> 6) << 4) | (w & 15);
        const int kc = (w >> 4) & 3;
        if (tile < 2) {
            int grow = rowBase + rl; if (grow >= M) grow = M - 1;
            srcs[t] = (tile == 0 ? Ah : Al) + (size_t)grow * K + kc * 8;
        } else {
            const int gcol = colBase + rl;
            srcs[t] = (tile == 2 ? Bh : Bl) + (size_t)gcol * K + kc * 8;
        }
    }

    const int lane = tid & 63, wid = tid >> 6;
    const int wr = wid >> 1, wc = wid & 1;
    const int lr = lane & 15, lk = lane >> 4;

    f32x4 acc[4][4];
#pragma unroll
    for (int i = 0; i < 4; ++i)
#pragma unroll
        for (int j = 0; j < 4; ++j) acc[i][j] = (f32x4){0.f, 0.f, 0.f, 0.f};

    const int NT = K >> 5;   // K/32 tiles

    // prologue: stage tile 0
#pragma unroll
    for (int t = 0; t < 8; ++t)
        load_lds16(srcs[t], &lds[0][tid + t * 256]);
    __syncthreads();

    int cur = 0;
    for (int kt = 1; kt <= NT; ++kt) {
        // issue next tile's loads into the other buffer (latency hides under compute)
        if (kt < NT) {
#pragma unroll
            for (int t = 0; t < 8; ++t)
                load_lds16(srcs[t] + kt * 32, &lds[cur ^ 1][tid + t * 256]);
        }

        bf16x8 ah[4], al[4], bh[4], bl[4];
#pragma unroll
        for (int i = 0; i < 4; ++i) {
            const int am = ((wr * 4 + i) * 4 + lk) * 16 + lr;
            ah[i] = lds[cur][0 * 512 + am];
            al[i] = lds[cur][1 * 512 + am];
            const int bn = ((wc * 4 + i) * 4 + lk) * 16 + lr;
            bh[i] = lds[cur][2 * 512 + bn];
            bl[i] = lds[cur][3 * 512 + bn];
        }
#pragma unroll
        for (int mi = 0; mi < 4; ++mi)
#pragma unroll
            for (int ni = 0; ni < 4; ++ni) {
                acc[mi][ni] = __builtin_amdgcn_mfma_f32_16x16x32_bf16(ah[mi], bh[ni], acc[mi][ni], 0, 0, 0);
                acc[mi][ni] = __builtin_amdgcn_mfma_f32_16x16x32_bf16(ah[mi], bl[ni], acc[mi][ni], 0, 0, 0);
                acc[mi][ni] = __builtin_amdgcn_mfma_f32_16x16x32_bf16(al[mi], bh[ni], acc[mi][ni], 0, 0, 0);
            }

        // implicit vmcnt(0)+lgkmcnt(0) drain: next tile landed, this tile's reads done
        __syncthreads();
        cur ^= 1;
    }

    // C/D: col = lane&15, row = (lane>>4)*4 + i
    const int rbase = rowBase + wr * 64 + lk * 4;
    if (MODE == 0) {
#pragma unroll
        for (int mi = 0; mi < 4; ++mi)
#pragma unroll
            for (int ni = 0; ni < 4; ++ni) {
                const int c = colBase + wc * 64 + ni * 16 + lr;
                const float bv = bias[c];
#pragma unroll
                for (int i = 0; i < 4; ++i) {
                    const int r = rbase + mi * 16 + i;
                    if (r < M) C0[(size_t)r * Nn + c] = acc[mi][ni][i] + bv;
                }
            }
    } else {
#pragma unroll
        for (int ni = 0; ni < 4; ++ni) {
            const int c0 = colBase + wc * 64 + ni * 16;
            const int s = c0 / DIM;
            const int rem = c0 - s * DIM;
            const int hh = rem >> 6;
            const int d = (rem & 63) + lr;
            unsigned short* dst = (s == 0) ? Cq : (s == 1) ? Ck : Cv;
            const float mul = (s == 0) ? 0.125f : 1.0f;   // q pre-scaled by 64^-0.5
            const float bv = bias[c0 + lr];
#pragma unroll
            for (int mi = 0; mi < 4; ++mi)
#pragma unroll
                for (int i = 0; i < 4; ++i) {
                    const int r = rbase + mi * 16 + i;
                    if (r < M) {
                        const int bb = r / NTOK;
                        const int nn = r - bb * NTOK;
                        dst[(((size_t)(bb * NHEADS + hh) * NTOK + nn) << 6) + d] =
                            f2bf((acc[mi][ni][i] + bv) * mul);
                    }
                }
        }
    }
}

// ---------------- bias pre-gather in MFMA fragment order ----------------
// biasF[h][kt(7)][qt(13)][kn(2)][lane(64)][i(4)] bf16; -60 for OOB keys (kills pad via exp)
#define BIASF_U4 (NHEADS * 7 * 13 * 2 * 64)   // 139776 ushort4's
__global__ __launch_bounds__(256)
void biasF_pre(const float* __restrict__ table, const int* __restrict__ ridx,
               ushort4* __restrict__ biasF)
{
    const int idx = blockIdx.x * 256 + threadIdx.x;
    if (idx >= BIASF_U4) return;
    const int l  = idx & 63;
    int t1 = idx >> 6;
    const int kn = t1 & 1;  t1 >>= 1;
    const int qt = t1 % 13; t1 /= 13;
    const int kt = t1 % 7;
    const int h  = t1 / 7;
    const int k = kt * 32 + kn * 16 + (l & 15);
    ushort4 o;
    unsigned short* op = (unsigned short*)&o;
#pragma unroll
    for (int i = 0; i < 4; ++i) {
        const int q = qt * 16 + (l >> 4) * 4 + i;
        float v = -60.0f;
        if (q < NTOK && k < NTOK) v = table[ridx[q * NTOK + k] * NHEADS + h];
        op[i] = f2bf(v);
    }
    biasF[idx] = o;
}

// ---------------- MFMA flash attention: block = (b,h), 4 waves x 64 queries ----------------
__global__ __launch_bounds__(256, 2)
void attn_mfma(const unsigned short* __restrict__ Q, const unsigned short* __restrict__ K,
               const unsigned short* __restrict__ V, const unsigned short* __restrict__ biasF,
               unsigned short* __restrict__ Oh, unsigned short* __restrict__ Ol)
{
    __shared__ unsigned short Kb[32 * 64];        // 4 KB, xor-swizzled columns
    __shared__ unsigned short Vt[64 * 40];        // 5 KB, padded V^T
    __shared__ unsigned short Pb[4][64 * 40];     // 20.5 KB, per-wave P

    const int bh = blockIdx.x;
    const int b = bh / NHEADS, h = bh - b * NHEADS;
    const int tid = threadIdx.x;
    const int w = tid >> 6, l = tid & 63;
    const int g = l >> 4, r = l & 15;
    const int nmt = (w < 3) ? 4 : 1;              // wave 3: only m-tile 12 (rows 192-196)

    const unsigned short* qb    = Q + (size_t)bh * NTOK * 64;
    const unsigned short* kbase = K + (size_t)bh * NTOK * 64;
    const unsigned short* vbase = V + (size_t)bh * NTOK * 64;

    // Q fragments: row = lane&15, k(d) = (lane>>4)*8+j
    bf16x8 qa[4][2];
#pragma unroll
    for (int mt = 0; mt < 4; ++mt) {
        if (mt >= nmt) break;
        int qrow = 64 * w + 16 * mt + r; if (qrow > 196) qrow = 196;
#pragma unroll
        for (int kd = 0; kd < 2; ++kd)
            qa[mt][kd] = *(const bf16x8*)&qb[qrow * 64 + kd * 32 + g * 8];
    }

    f32x4 o[4][4];
#pragma unroll
    for (int mt = 0; mt < 4; ++mt)
#pragma unroll
        for (int dt = 0; dt < 4; ++dt) o[mt][dt] = (f32x4){0.f, 0.f, 0.f, 0.f};
    float lsum[4][4] = {};

    // staging geometry
    const int krow = tid >> 3;                    // 0..31
    const int kcl  = (tid & 7) * 8;               // physical col (ushorts)
    const int kcg  = kcl ^ ((krow & 7) << 3);     // logical col at this slot
    const int vdd  = tid >> 2;                    // 0..63
    const int vkg  = tid & 3;

    const ushort4* bF4 = (const ushort4*)biasF;

    for (int kt = 0; kt < 7; ++kt) {
        __syncthreads();
        // K stage: LDS linear, source pre-swizzled
        int key = kt * 32 + krow; if (key > 196) key = 196;
        load_lds16(kbase + (size_t)key * 64 + kcg, &Kb[tid * 8]);
        // V^T stage: gather 8 keys for one d
        bf16x8 vv;
        unsigned short* vp = (unsigned short*)&vv;
#pragma unroll
        for (int j = 0; j < 8; ++j) {
            int kj = kt * 32 + vkg * 8 + j; if (kj > 196) kj = 196;
            vp[j] = vbase[(size_t)kj * 64 + vdd];
        }
        *(bf16x8*)&Vt[vdd * 40 + vkg * 8] = vv;
        asm volatile("s_waitcnt vmcnt(0)" ::: "memory");
        __syncthreads();

        // K b-frags (shared across m-tiles)
        bf16x8 kb[2][2];
#pragma unroll
        for (int kn = 0; kn < 2; ++kn)
#pragma unroll
            for (int kd = 0; kd < 2; ++kd)
                kb[kn][kd] = *(bf16x8*)&Kb[(kn * 16 + r) * 64 + ((kd * 32 + g * 8) ^ ((r & 7) << 3))];

        // scores + softmax numerator + P to LDS
#pragma unroll
        for (int mt = 0; mt < 4; ++mt) {
            if (mt >= nmt) break;
            const int qt = w * 4 + mt;
#pragma unroll
            for (int kn = 0; kn < 2; ++kn) {
                f32x4 s = (f32x4){0.f, 0.f, 0.f, 0.f};
                s = __builtin_amdgcn_mfma_f32_16x16x32_bf16(qa[mt][0], kb[kn][0], s, 0, 0, 0);
                s = __builtin_amdgcn_mfma_f32_16x16x32_bf16(qa[mt][1], kb[kn][1], s, 0, 0, 0);
                const ushort4 bb = bF4[(((h * 7 + kt) * 13 + qt) * 2 + kn) * 64 + l];
                const unsigned short* bp = (const unsigned short*)&bb;
#pragma unroll
                for (int i = 0; i < 4; ++i) {
                    const float p = __expf(s[i] + bf2f(bp[i]));
                    lsum[mt][i] += p;
                    Pb[w][(mt * 16 + 4 * g + i) * 40 + kn * 16 + r] = f2bf(p);
                }
            }
        }

        // PV: o += P @ V  (K-dim = 32 keys in one mfma)
        bf16x8 vb[4];
#pragma unroll
        for (int dt = 0; dt < 4; ++dt)
            vb[dt] = *(bf16x8*)&Vt[(dt * 16 + r) * 40 + g * 8];
#pragma unroll
        for (int mt = 0; mt < 4; ++mt) {
            if (mt >= nmt) break;
            bf16x8 pa = *(bf16x8*)&Pb[w][(mt * 16 + r) * 40 + g * 8];
#pragma unroll
            for (int dt = 0; dt < 4; ++dt)
                o[mt][dt] = __builtin_amdgcn_mfma_f32_16x16x32_bf16(pa, vb[dt], o[mt][dt], 0, 0, 0);
        }
    }

    // reduce denominators across the 16 key-lanes
    float inv[4][4];
#pragma unroll
    for (int mt = 0; mt < 4; ++mt) {
        if (mt >= nmt) break;
#pragma unroll
        for (int i = 0; i < 4; ++i) {
            float t = lsum[mt][i];
            t += __shfl_xor(t, 1); t += __shfl_xor(t, 2);
            t += __shfl_xor(t, 4); t += __shfl_xor(t, 8);
            inv[mt][i] = 1.f / t;
        }
    }

    // write ao hi/lo bf16
#pragma unroll
    for (int mt = 0; mt < 4; ++mt) {
        if (mt >= nmt) break;
#pragma unroll
        for (int i = 0; i < 4; ++i) {
            const int q = 64 * w + mt * 16 + 4 * g + i;
            if (q > 196) continue;
            const size_t base = ((size_t)b * NTOK + q) * DIM + h * 64 + r;
#pragma unroll
            for (int dt = 0; dt < 4; ++dt) {
                const float val = o[mt][dt][i] * inv[mt][i];
                const unsigned short hb = f2bf(val);
                Oh[base + dt * 16] = hb;
                Ol[base + dt * 16] = f2bf(val - bf2f(hb));
            }
        }
    }
}

extern "C" void kernel_launch(void* const* d_in, const int* in_sizes, int n_in,
                              void* d_out, int out_size, void* d_ws, size_t ws_size,
                              hipStream_t stream)
{
    const float* x      = (const float*)d_in[0];
    const float* qkv_w  = (const float*)d_in[1];
    const float* qkv_b  = (const float*)d_in[2];
    const float* proj_w = (const float*)d_in[3];
    const float* proj_b = (const float*)d_in[4];
    const float* table  = (const float*)d_in[5];
    const int*   ridx   = (const int*)d_in[6];
    float* out = (float*)d_out;

    // workspace (~59 MB)
    char* p = (char*)d_ws;
    auto alloc = [&](size_t bytes) { char* r = p; p += (bytes + 255) & ~(size_t)255; return r; };
    unsigned short* wqh = (unsigned short*)alloc((size_t)3 * DIM * DIM * 2);
    unsigned short* wql = (unsigned short*)alloc((size_t)3 * DIM * DIM * 2);
    unsigned short* wph = (unsigned short*)alloc((size_t)DIM * DIM * 2);
    unsigned short* wpl = (unsigned short*)alloc((size_t)DIM * DIM * 2);
    ushort4*        bF  = (ushort4*)alloc((size_t)BIASF_U4 * 8);
    unsigned short* xh  = (unsigned short*)alloc((size_t)M_C * DIM * 2);   // reused as ao_hi
    unsigned short* xl  = (unsigned short*)alloc((size_t)M_C * DIM * 2);   // reused as ao_lo
    unsigned short* qd  = (unsigned short*)alloc((size_t)B_Q * NHEADS * NTOK * 64 * 2);
    unsigned short* kd  = (unsigned short*)alloc((size_t)B_Q * NHEADS * NTOK * 64 * 2);
    unsigned short* vd  = (unsigned short*)alloc((size_t)B_Q * NHEADS * NTOK * 64 * 2);

    split_bf16<<<(3 * DIM * DIM / 4 + 255) / 256, 256, 0, stream>>>(qkv_w, wqh, wql, 3 * DIM * DIM / 4);
    split_bf16<<<(DIM * DIM / 4 + 255) / 256, 256, 0, stream>>>(proj_w, wph, wpl, DIM * DIM / 4);
    biasF_pre<<<(BIASF_U4 + 255) / 256, 256, 0, stream>>>(table, ridx, bF);

    const int mtiles = (M_C + 127) / 128;   // 50
    for (int c = 0; c < NQUARTER; ++c) {
        const float* xc   = x   + (size_t)c * M_C * DIM;
        float*       outc = out + (size_t)c * M_C * DIM;

        split_bf16<<<(M_C * DIM / 4 + 255) / 256, 256, 0, stream>>>(xc, xh, xl, M_C * DIM / 4);

        gemm_bf16x3<1><<<dim3(3 * DIM / 128, mtiles), 256, 0, stream>>>(
            xh, xl, wqh, wql, qkv_b, nullptr, qd, kd, vd, M_C, 3 * DIM, DIM);

        attn_mfma<<<B_Q * NHEADS, 256, 0, stream>>>(qd, kd, vd,
                                                    (const unsigned short*)bF, xh, xl);

        gemm_bf16x3<0><<<dim3(DIM / 128, mtiles), 256, 0, stream>>>(
            xh, xl, wph, wpl, proj_b, outc, nullptr, nullptr, nullptr, M_C, DIM, DIM);
    }
}

// Round 11
// 919.878 us; speedup vs baseline: 3.0128x; 1.0325x over previous
//
#include <hip/hip_runtime.h>
#include <stdint.h>

#define DIM 768
#define NHEADS 12
#define NTOK 197
#define BATCH 128
#define B_Q 32                      // quarter-batch
#define NQUARTER (BATCH / B_Q)
#define M_C (B_Q * NTOK)            // 6304 rows per quarter

typedef __attribute__((ext_vector_type(8))) short bf16x8;
typedef __attribute__((ext_vector_type(4))) float f32x4;

__device__ __forceinline__ unsigned short f2bf(float f) {
    unsigned u = __float_as_uint(f);
    return (unsigned short)((u + 0x7FFFu + ((u >> 16) & 1u)) >> 16);  // RNE
}
__device__ __forceinline__ float bf2f(unsigned short h) {
    return __uint_as_float(((unsigned)h) << 16);
}

__device__ __forceinline__ void load_lds16(const void* g, void* l) {
    __builtin_amdgcn_global_load_lds(
        (const __attribute__((address_space(1))) unsigned int*)(uintptr_t)g,
        (__attribute__((address_space(3))) unsigned int*)(uintptr_t)l, 16, 0, 0);
}

// ---------------- split fp32 -> bf16 hi/lo ----------------
__global__ __launch_bounds__(256) void split_bf16(const float* __restrict__ in,
                                                  unsigned short* __restrict__ hi,
                                                  unsigned short* __restrict__ lo, int n4)
{
    const int i = blockIdx.x * 256 + threadIdx.x;
    if (i >= n4) return;
    float4 v = ((const float4*)in)[i];
    ushort4 h, l;
    h.x = f2bf(v.x); l.x = f2bf(v.x - bf2f(h.x));
    h.y = f2bf(v.y); l.y = f2bf(v.y - bf2f(h.y));
    h.z = f2bf(v.z); l.z = f2bf(v.z - bf2f(h.z));
    h.w = f2bf(v.w); l.w = f2bf(v.w - bf2f(h.w));
    ((ushort4*)hi)[i] = h;
    ((ushort4*)lo)[i] = l;
}

// ---------------- bf16x3 MFMA GEMM: C = (Ah+Al) @ (Bh+Bl)^T + bias ----------------
// T4 counted-vmcnt pipeline: raw s_barrier, 2-tile-deep prefetch, vmcnt(8) (never 0
// in steady state). + bijective XCD swizzle (T1/m204).
// MODE 0: fp32 C0[M,Nn].  MODE 1: qkv scatter to bf16 q/k/v [B_Q,H,N,64], q pre-scaled.
template<int MODE>
__global__ __launch_bounds__(256)
void gemm_bf16x3(const unsigned short* __restrict__ Ah, const unsigned short* __restrict__ Al,
                 const unsigned short* __restrict__ Bh, const unsigned short* __restrict__ Bl,
                 const float* __restrict__ bias,
                 float* __restrict__ C0, unsigned short* __restrict__ Cq,
                 unsigned short* __restrict__ Ck, unsigned short* __restrict__ Cv,
                 int M, int Nn, int K)
{
    __shared__ bf16x8 lds[2][2048];   // 64 KB double-buffered
    const int tid = threadIdx.x;

    // bijective XCD swizzle: contiguous wg-chunk per XCD -> A-panel L2 locality
    const int gx = gridDim.x;
    const int nwg = gx * gridDim.y;
    const int orig = blockIdx.y * gx + blockIdx.x;
    const int q8 = nwg >> 3, r8 = nwg & 7;
    const int xcd = orig & 7, pos = orig >> 3;
    const int wg = (xcd < r8 ? xcd * (q8 + 1) : r8 * (q8 + 1) + (xcd - r8) * q8) + pos;
    const int rowBase = (wg / gx) * 128;
    const int colBase = (wg % gx) * 128;

    const unsigned short* srcs[8];
#pragma unroll
    for (int t = 0; t < 8; ++t) {
        const int s = tid + t * 256;
        const int tile = s >> 9;          // 0:Ah 1:Al 2:Bh 3:Bl
        const int w = s & 511;
        const int rl = ((w >> 6) << 4) | (w & 15);
        const int kc = (w >> 4) & 3;
        if (tile < 2) {
            int grow = rowBase + rl; if (grow >= M) grow = M - 1;
            srcs[t] = (tile == 0 ? Ah : Al) + (size_t)grow * K + kc * 8;
        } else {
            const int gcol = colBase + rl;
            srcs[t] = (tile == 2 ? Bh : Bl) + (size_t)gcol * K + kc * 8;
        }
    }

    const int lane = tid & 63, wid = tid >> 6;
    const int wr = wid >> 1, wc = wid & 1;
    const int lr = lane & 15, lk = lane >> 4;

    f32x4 acc[4][4];
#pragma unroll
    for (int i = 0; i < 4; ++i)
#pragma unroll
        for (int j = 0; j < 4; ++j) acc[i][j] = (f32x4){0.f, 0.f, 0.f, 0.f};

    const int NT = K >> 5;   // K/32 tiles (24)

    // prologue: stage tiles 0 and 1 (16 loads in flight/thread)
#pragma unroll
    for (int t = 0; t < 8; ++t)
        load_lds16(srcs[t], &lds[0][tid + t * 256]);
#pragma unroll
    for (int t = 0; t < 8; ++t)
        load_lds16(srcs[t] + 32, &lds[1][tid + t * 256]);
    asm volatile("s_waitcnt vmcnt(8)" ::: "memory");   // tile 0 landed (tile 1 in flight)
    __builtin_amdgcn_sched_barrier(0);
    __builtin_amdgcn_s_barrier();

    int cur = 0;
    for (int kt = 0; kt < NT; ++kt) {
        bf16x8 ah[4], al[4], bh[4], bl[4];
#pragma unroll
        for (int i = 0; i < 4; ++i) {
            const int am = ((wr * 4 + i) * 4 + lk) * 16 + lr;
            ah[i] = lds[cur][0 * 512 + am];
            al[i] = lds[cur][1 * 512 + am];
            const int bn = ((wc * 4 + i) * 4 + lk) * 16 + lr;
            bh[i] = lds[cur][2 * 512 + bn];
            bl[i] = lds[cur][3 * 512 + bn];
        }
#pragma unroll
        for (int mi = 0; mi < 4; ++mi)
#pragma unroll
            for (int ni = 0; ni < 4; ++ni) {
                acc[mi][ni] = __builtin_amdgcn_mfma_f32_16x16x32_bf16(ah[mi], bh[ni], acc[mi][ni], 0, 0, 0);
                acc[mi][ni] = __builtin_amdgcn_mfma_f32_16x16x32_bf16(ah[mi], bl[ni], acc[mi][ni], 0, 0, 0);
                acc[mi][ni] = __builtin_amdgcn_mfma_f32_16x16x32_bf16(al[mi], bh[ni], acc[mi][ni], 0, 0, 0);
            }

        if (kt == NT - 1) break;

        // barrier A: every wave's ds_reads of buf[cur] are complete (lgkm drained by
        // MFMA data deps) -> safe to overwrite buf[cur] with tile kt+2.
        __builtin_amdgcn_sched_barrier(0);
        __builtin_amdgcn_s_barrier();
        if (kt + 2 < NT) {
#pragma unroll
            for (int t = 0; t < 8; ++t)
                load_lds16(srcs[t] + (kt + 2) * 32, &lds[cur][tid + t * 256]);
            // wait for MY tile kt+1 loads (8 newest = kt+2's stay in flight)
            asm volatile("s_waitcnt vmcnt(8)" ::: "memory");
        } else {
            asm volatile("s_waitcnt vmcnt(0)" ::: "memory");   // once, at kt = NT-2
        }
        __builtin_amdgcn_sched_barrier(0);
        // barrier B: ALL waves' kt+1 loads landed -> buf[cur^1] readable
        __builtin_amdgcn_s_barrier();
        cur ^= 1;
    }

    // C/D: col = lane&15, row = (lane>>4)*4 + i
    const int rbase = rowBase + wr * 64 + lk * 4;
    if (MODE == 0) {
#pragma unroll
        for (int mi = 0; mi < 4; ++mi)
#pragma unroll
            for (int ni = 0; ni < 4; ++ni) {
                const int c = colBase + wc * 64 + ni * 16 + lr;
                const float bv = bias[c];
#pragma unroll
                for (int i = 0; i < 4; ++i) {
                    const int r = rbase + mi * 16 + i;
                    if (r < M) C0[(size_t)r * Nn + c] = acc[mi][ni][i] + bv;
                }
            }
    } else {
#pragma unroll
        for (int ni = 0; ni < 4; ++ni) {
            const int c0 = colBase + wc * 64 + ni * 16;
            const int s = c0 / DIM;
            const int rem = c0 - s * DIM;
            const int hh = rem >> 6;
            const int d = (rem & 63) + lr;
            unsigned short* dst = (s == 0) ? Cq : (s == 1) ? Ck : Cv;
            const float mul = (s == 0) ? 0.125f : 1.0f;   // q pre-scaled by 64^-0.5
            const float bv = bias[c0 + lr];
#pragma unroll
            for (int mi = 0; mi < 4; ++mi)
#pragma unroll
                for (int i = 0; i < 4; ++i) {
                    const int r = rbase + mi * 16 + i;
                    if (r < M) {
                        const int bb = r / NTOK;
                        const int nn = r - bb * NTOK;
                        dst[(((size_t)(bb * NHEADS + hh) * NTOK + nn) << 6) + d] =
                            f2bf((acc[mi][ni][i] + bv) * mul);
                    }
                }
        }
    }
}

// ---------------- bias pre-gather in MFMA fragment order ----------------
// biasF[h][kt(7)][qt(13)][kn(2)][lane(64)][i(4)] bf16; -60 for OOB keys (kills pad via exp)
#define BIASF_U4 (NHEADS * 7 * 13 * 2 * 64)   // 139776 ushort4's
__global__ __launch_bounds__(256)
void biasF_pre(const float* __restrict__ table, const int* __restrict__ ridx,
               ushort4* __restrict__ biasF)
{
    const int idx = blockIdx.x * 256 + threadIdx.x;
    if (idx >= BIASF_U4) return;
    const int l  = idx & 63;
    int t1 = idx >> 6;
    const int kn = t1 & 1;  t1 >>= 1;
    const int qt = t1 % 13; t1 /= 13;
    const int kt = t1 % 7;
    const int h  = t1 / 7;
    const int k = kt * 32 + kn * 16 + (l & 15);
    ushort4 o;
    unsigned short* op = (unsigned short*)&o;
#pragma unroll
    for (int i = 0; i < 4; ++i) {
        const int q = qt * 16 + (l >> 4) * 4 + i;
        float v = -60.0f;
        if (q < NTOK && k < NTOK) v = table[ridx[q * NTOK + k] * NHEADS + h];
        op[i] = f2bf(v);
    }
    biasF[idx] = o;
}

// ---------------- MFMA flash attention: block = (b,h), 4 waves x 64 queries ----------------
__global__ __launch_bounds__(256, 2)
void attn_mfma(const unsigned short* __restrict__ Q, const unsigned short* __restrict__ K,
               const unsigned short* __restrict__ V, const unsigned short* __restrict__ biasF,
               unsigned short* __restrict__ Oh, unsigned short* __restrict__ Ol)
{
    __shared__ unsigned short Kb[32 * 64];        // 4 KB, xor-swizzled columns
    __shared__ unsigned short Vt[64 * 40];        // 5 KB, padded V^T
    __shared__ unsigned short Pb[4][64 * 40];     // 20.5 KB, per-wave P

    const int bh = blockIdx.x;
    const int b = bh / NHEADS, h = bh - b * NHEADS;
    const int tid = threadIdx.x;
    const int w = tid >> 6, l = tid & 63;
    const int g = l >> 4, r = l & 15;
    const int nmt = (w < 3) ? 4 : 1;              // wave 3: only m-tile 12 (rows 192-196)

    const unsigned short* qb    = Q + (size_t)bh * NTOK * 64;
    const unsigned short* kbase = K + (size_t)bh * NTOK * 64;
    const unsigned short* vbase = V + (size_t)bh * NTOK * 64;

    // Q fragments: row = lane&15, k(d) = (lane>>4)*8+j
    bf16x8 qa[4][2];
#pragma unroll
    for (int mt = 0; mt < 4; ++mt) {
        if (mt >= nmt) break;
        int qrow = 64 * w + 16 * mt + r; if (qrow > 196) qrow = 196;
#pragma unroll
        for (int kd = 0; kd < 2; ++kd)
            qa[mt][kd] = *(const bf16x8*)&qb[qrow * 64 + kd * 32 + g * 8];
    }

    f32x4 o[4][4];
#pragma unroll
    for (int mt = 0; mt < 4; ++mt)
#pragma unroll
        for (int dt = 0; dt < 4; ++dt) o[mt][dt] = (f32x4){0.f, 0.f, 0.f, 0.f};
    float lsum[4][4] = {};

    // staging geometry
    const int krow = tid >> 3;                    // 0..31
    const int kcl  = (tid & 7) * 8;               // physical col (ushorts)
    const int kcg  = kcl ^ ((krow & 7) << 3);     // logical col at this slot
    const int vdd  = tid >> 2;                    // 0..63
    const int vkg  = tid & 3;

    const ushort4* bF4 = (const ushort4*)biasF;

    for (int kt = 0; kt < 7; ++kt) {
        __syncthreads();
        // K stage: LDS linear, source pre-swizzled
        int key = kt * 32 + krow; if (key > 196) key = 196;
        load_lds16(kbase + (size_t)key * 64 + kcg, &Kb[tid * 8]);
        // V^T stage: gather 8 keys for one d
        bf16x8 vv;
        unsigned short* vp = (unsigned short*)&vv;
#pragma unroll
        for (int j = 0; j < 8; ++j) {
            int kj = kt * 32 + vkg * 8 + j; if (kj > 196) kj = 196;
            vp[j] = vbase[(size_t)kj * 64 + vdd];
        }
        *(bf16x8*)&Vt[vdd * 40 + vkg * 8] = vv;
        asm volatile("s_waitcnt vmcnt(0)" ::: "memory");
        __syncthreads();

        // K b-frags (shared across m-tiles)
        bf16x8 kb[2][2];
#pragma unroll
        for (int kn = 0; kn < 2; ++kn)
#pragma unroll
            for (int kd = 0; kd < 2; ++kd)
                kb[kn][kd] = *(bf16x8*)&Kb[(kn * 16 + r) * 64 + ((kd * 32 + g * 8) ^ ((r & 7) << 3))];

        // scores + softmax numerator + P to LDS
#pragma unroll
        for (int mt = 0; mt < 4; ++mt) {
            if (mt >= nmt) break;
            const int qt = w * 4 + mt;
#pragma unroll
            for (int kn = 0; kn < 2; ++kn) {
                f32x4 s = (f32x4){0.f, 0.f, 0.f, 0.f};
                s = __builtin_amdgcn_mfma_f32_16x16x32_bf16(qa[mt][0], kb[kn][0], s, 0, 0, 0);
                s = __builtin_amdgcn_mfma_f32_16x16x32_bf16(qa[mt][1], kb[kn][1], s, 0, 0, 0);
                const ushort4 bb = bF4[(((h * 7 + kt) * 13 + qt) * 2 + kn) * 64 + l];
                const unsigned short* bp = (const unsigned short*)&bb;
#pragma unroll
                for (int i = 0; i < 4; ++i) {
                    const float p = __expf(s[i] + bf2f(bp[i]));
                    lsum[mt][i] += p;
                    Pb[w][(mt * 16 + 4 * g + i) * 40 + kn * 16 + r] = f2bf(p);
                }
            }
        }

        // PV: o += P @ V  (K-dim = 32 keys in one mfma)
        bf16x8 vb[4];
#pragma unroll
        for (int dt = 0; dt < 4; ++dt)
            vb[dt] = *(bf16x8*)&Vt[(dt * 16 + r) * 40 + g * 8];
#pragma unroll
        for (int mt = 0; mt < 4; ++mt) {
            if (mt >= nmt) break;
            bf16x8 pa = *(bf16x8*)&Pb[w][(mt * 16 + r) * 40 + g * 8];
#pragma unroll
            for (int dt = 0; dt < 4; ++dt)
                o[mt][dt] = __builtin_amdgcn_mfma_f32_16x16x32_bf16(pa, vb[dt], o[mt][dt], 0, 0, 0);
        }
    }

    // reduce denominators across the 16 key-lanes
    float inv[4][4];
#pragma unroll
    for (int mt = 0; mt < 4; ++mt) {
        if (mt >= nmt) break;
#pragma unroll
        for (int i = 0; i < 4; ++i) {
            float t = lsum[mt][i];
            t += __shfl_xor(t, 1); t += __shfl_xor(t, 2);
            t += __shfl_xor(t, 4); t += __shfl_xor(t, 8);
            inv[mt][i] = 1.f / t;
        }
    }

    // write ao hi/lo bf16
#pragma unroll
    for (int mt = 0; mt < 4; ++mt) {
        if (mt >= nmt) break;
#pragma unroll
        for (int i = 0; i < 4; ++i) {
            const int q = 64 * w + mt * 16 + 4 * g + i;
            if (q > 196) continue;
            const size_t base = ((size_t)b * NTOK + q) * DIM + h * 64 + r;
#pragma unroll
            for (int dt = 0; dt < 4; ++dt) {
                const float val = o[mt][dt][i] * inv[mt][i];
                const unsigned short hb = f2bf(val);
                Oh[base + dt * 16] = hb;
                Ol[base + dt * 16] = f2bf(val - bf2f(hb));
            }
        }
    }
}

extern "C" void kernel_launch(void* const* d_in, const int* in_sizes, int n_in,
                              void* d_out, int out_size, void* d_ws, size_t ws_size,
                              hipStream_t stream)
{
    const float* x      = (const float*)d_in[0];
    const float* qkv_w  = (const float*)d_in[1];
    const float* qkv_b  = (const float*)d_in[2];
    const float* proj_w = (const float*)d_in[3];
    const float* proj_b = (const float*)d_in[4];
    const float* table  = (const float*)d_in[5];
    const int*   ridx   = (const int*)d_in[6];
    float* out = (float*)d_out;

    // workspace (~59 MB)
    char* p = (char*)d_ws;
    auto alloc = [&](size_t bytes) { char* r = p; p += (bytes + 255) & ~(size_t)255; return r; };
    unsigned short* wqh = (unsigned short*)alloc((size_t)3 * DIM * DIM * 2);
    unsigned short* wql = (unsigned short*)alloc((size_t)3 * DIM * DIM * 2);
    unsigned short* wph = (unsigned short*)alloc((size_t)DIM * DIM * 2);
    unsigned short* wpl = (unsigned short*)alloc((size_t)DIM * DIM * 2);
    ushort4*        bF  = (ushort4*)alloc((size_t)BIASF_U4 * 8);
    unsigned short* xh  = (unsigned short*)alloc((size_t)M_C * DIM * 2);   // reused as ao_hi
    unsigned short* xl  = (unsigned short*)alloc((size_t)M_C * DIM * 2);   // reused as ao_lo
    unsigned short* qd  = (unsigned short*)alloc((size_t)B_Q * NHEADS * NTOK * 64 * 2);
    unsigned short* kd  = (unsigned short*)alloc((size_t)B_Q * NHEADS * NTOK * 64 * 2);
    unsigned short* vd  = (unsigned short*)alloc((size_t)B_Q * NHEADS * NTOK * 64 * 2);

    split_bf16<<<(3 * DIM * DIM / 4 + 255) / 256, 256, 0, stream>>>(qkv_w, wqh, wql, 3 * DIM * DIM / 4);
    split_bf16<<<(DIM * DIM / 4 + 255) / 256, 256, 0, stream>>>(proj_w, wph, wpl, DIM * DIM / 4);
    biasF_pre<<<(BIASF_U4 + 255) / 256, 256, 0, stream>>>(table, ridx, bF);

    const int mtiles = (M_C + 127) / 128;   // 50
    for (int c = 0; c < NQUARTER; ++c) {
        const float* xc   = x   + (size_t)c * M_C * DIM;
        float*       outc = out + (size_t)c * M_C * DIM;

        split_bf16<<<(M_C * DIM / 4 + 255) / 256, 256, 0, stream>>>(xc, xh, xl, M_C * DIM / 4);

        gemm_bf16x3<1><<<dim3(3 * DIM / 128, mtiles), 256, 0, stream>>>(
            xh, xl, wqh, wql, qkv_b, nullptr, qd, kd, vd, M_C, 3 * DIM, DIM);

        attn_mfma<<<B_Q * NHEADS, 256, 0, stream>>>(qd, kd, vd,
                                                    (const unsigned short*)bF, xh, xl);

        gemm_bf16x3<0><<<dim3(DIM / 128, mtiles), 256, 0, stream>>>(
            xh, xl, wph, wpl, proj_b, outc, nullptr, nullptr, nullptr, M_C, DIM, DIM);
    }
}